// Round 11
// baseline (534.090 us; speedup 1.0000x reference)
//
#include <hip/hip_runtime.h>

#define N_NODES 100000
#define N_EDGES 3200000
#define BATCH 16
#define BKT_SHIFT 6
#define BKT_NODES 64
#define K_BUCKETS 1563                 // ceil(100000/64)
#define NB 256                         // subchunks (E/NB = 12500 exact)
#define SUB (N_EDGES / NB)             // 12500
#define FT 512                         // fill threads per block
#define SCAN_T 256
#define SCAN_C 7                       // 256*7 = 1792 >= 1563
#define CAP 4096                       // nodesort LDS capacity (bucket avg 2047, sigma 45)
#define GSLICE (N_NODES * 8)           // floats per column-group slice
#define NODEBLKS 3125                  // 100000 / 32 nodes per block

// ---- phase 1: per-subchunk LDS histogram of row-buckets ----
__global__ void hist_kernel(const int* __restrict__ row, int* __restrict__ blk_cnt) {
    __shared__ int lh[K_BUCKETS];
    int t = threadIdx.x, blk = blockIdx.x;
    for (int k = t; k < K_BUCKETS; k += 256) lh[k] = 0;
    __syncthreads();
    int base = blk * SUB;
    for (int e = base + t; e < base + SUB; e += 256)
        atomicAdd(&lh[row[e] >> BKT_SHIFT], 1);
    __syncthreads();
    for (int k = t; k < K_BUCKETS; k += 256)
        blk_cnt[k * NB + blk] = lh[k];
}

// ---- phase 2: per-bucket exclusive prefix over the NB subchunks; totals ----
__global__ void colscan_kernel(int* __restrict__ blk_cnt, int* __restrict__ totals) {
    int bkt = blockIdx.x * blockDim.x + threadIdx.x;
    if (bkt >= K_BUCKETS) return;
    int4* p = (int4*)&blk_cnt[bkt * NB];
    int acc = 0;
    for (int q = 0; q < NB / 4; q++) {
        int4 v = p[q];
        int4 o;
        o.x = acc; acc += v.x;
        o.y = acc; acc += v.y;
        o.z = acc; acc += v.z;
        o.w = acc; acc += v.w;
        p[q] = o;
    }
    totals[bkt] = acc;
}

// ---- phase 3: exclusive scan of 1563 bucket totals -> bptr ----
__global__ void scan_kernel(const int* __restrict__ totals, int* __restrict__ bptr,
                            int* __restrict__ row_ptr) {
    __shared__ int s[SCAN_T];
    int t = threadIdx.x;
    int loc[SCAN_C];
    int sum = 0;
    for (int i = 0; i < SCAN_C; i++) {
        int idx = t * SCAN_C + i;
        int v = (idx < K_BUCKETS) ? totals[idx] : 0;
        loc[i] = v;
        sum += v;
    }
    s[t] = sum;
    __syncthreads();
    for (int off = 1; off < SCAN_T; off <<= 1) {   // Hillis-Steele inclusive
        int x = (t >= off) ? s[t - off] : 0;
        __syncthreads();
        s[t] += x;
        __syncthreads();
    }
    int excl = s[t] - sum;
    for (int i = 0; i < SCAN_C; i++) {
        int idx = t * SCAN_C + i;
        if (idx < K_BUCKETS) bptr[idx] = excl;
        excl += loc[i];
    }
    if (t == 0) { bptr[K_BUCKETS] = N_EDGES; row_ptr[N_NODES] = N_EDGES; }
}

// ---- phase 4: LDS counting sort per 12500-edge subchunk, then run copy-out.
// record: x = (r_local<<17)|col (col<2^17), y = w bits.
__global__ void __launch_bounds__(FT) fill_kernel(
        const int* __restrict__ row, const int* __restrict__ col,
        const float* __restrict__ w,
        const int* __restrict__ bptr, const int* __restrict__ blk_cnt,
        uint2* __restrict__ entries) {
    __shared__ uint2 sbuf[SUB];          // 100000 B
    __shared__ int lbeg[K_BUCKETS];      // 6252 B
    __shared__ int lcur[K_BUCKETS];      // 6252 B
    __shared__ int sscan[FT];            // 2048 B   (total 114.5 KB)
    int t = threadIdx.x, blk = blockIdx.x;
    for (int k = t; k < K_BUCKETS; k += FT) lcur[k] = 0;
    __syncthreads();
    int base = blk * SUB;
    for (int e = base + t; e < base + SUB; e += FT)
        atomicAdd(&lcur[row[e] >> BKT_SHIFT], 1);
    __syncthreads();
    int loc[4];
    int sum = 0;
    #pragma unroll
    for (int j = 0; j < 4; j++) {
        int k = t * 4 + j;
        int v = (k < K_BUCKETS) ? lcur[k] : 0;
        loc[j] = v;
        sum += v;
    }
    sscan[t] = sum;
    __syncthreads();
    for (int off = 1; off < FT; off <<= 1) {
        int x = (t >= off) ? sscan[t - off] : 0;
        __syncthreads();
        sscan[t] += x;
        __syncthreads();
    }
    int excl = sscan[t] - sum;
    #pragma unroll
    for (int j = 0; j < 4; j++) {
        int k = t * 4 + j;
        if (k < K_BUCKETS) { lbeg[k] = excl; lcur[k] = excl; }
        excl += loc[j];
    }
    __syncthreads();
    for (int e = base + t; e < base + SUB; e += FT) {
        int r = row[e];
        int bkt = r >> BKT_SHIFT;
        int pos = atomicAdd(&lcur[bkt], 1);
        sbuf[pos] = make_uint2(((unsigned)(r & (BKT_NODES - 1)) << 17) | (unsigned)col[e],
                               __float_as_uint(w[e]));
    }
    __syncthreads();
    int lane = t & 7;
    for (int k = (t >> 3); k < K_BUCKETS; k += FT / 8) {
        int lb = lbeg[k];
        int le = lcur[k];
        int dst = bptr[k] + blk_cnt[k * NB + blk];
        for (int i = lb + lane; i < le; i += 8)
            entries[dst + (i - lb)] = sbuf[i];
    }
}

// ---- phase 5: in-place per-bucket sort by node (LDS-staged); emits row_ptr ----
__global__ void nodesort_kernel(const int* __restrict__ bptr, uint2* __restrict__ entries,
                                int* __restrict__ row_ptr) {
    __shared__ uint2 ebuf[CAP];          // 32 KB
    __shared__ int nh[BKT_NODES];
    __shared__ int nc[BKT_NODES];
    int t = threadIdx.x, b = blockIdx.x;
    int beg = bptr[b], end = bptr[b + 1];
    int n = min(end - beg, CAP);
    if (t < BKT_NODES) nh[t] = 0;
    __syncthreads();
    for (int k = t; k < n; k += 256) {
        uint2 r = entries[beg + k];
        ebuf[k] = r;
        atomicAdd(&nh[r.x >> 17], 1);
    }
    __syncthreads();
    if (t == 0) {
        int acc = 0;
        for (int i = 0; i < BKT_NODES; i++) {
            int v = nh[i];
            int node = b * BKT_NODES + i;
            if (node < N_NODES) row_ptr[node] = beg + acc;
            nc[i] = acc;
            acc += v;
        }
    }
    __syncthreads();
    for (int k = t; k < n; k += 256) {
        uint2 r = ebuf[k];
        int pos = atomicAdd(&nc[r.x >> 17], 1);
        entries[beg + pos] = r;
    }
}

// ---- transpose x [node][16] -> split layout [grp][node][8] ----
__global__ void split_kernel(const float* __restrict__ x, float* __restrict__ yb) {
    int tid = blockIdx.x * blockDim.x + threadIdx.x;
    if (tid >= N_NODES * BATCH) return;
    int node = tid >> 4, c = tid & 15;
    yb[(c >> 3) * GSLICE + node * 8 + (c & 7)] = x[tid];
}

// nt load of an 8B record: keep the zero-reuse entries stream out of L2 so
// L2 keeps the L2-resident 3.2MB state slice.
__device__ __forceinline__ uint2 nt_load_u2(const uint2* p) {
    unsigned long long v = __builtin_nontemporal_load((const unsigned long long*)p);
    return make_uint2((unsigned)v, (unsigned)(v >> 32));
}

// ---- layer: column-sliced, XCD-pinned CSR pull ----
// Column group = bit2 of (blockIdx&7): with the MI300-family round-robin
// blockIdx%8 -> XCD mapping, XCDs 0-3 serve columns 0-7 and XCDs 4-7 serve
// columns 8-15. Per-XCD gather working set = 3.2MB < 4MB L2 -> gathers hit
// L2. Entries are nt-loaded (zero reuse per XCD); intermediate stores are nt
// (write-allocate would evict the read slice). 8 lanes per node, 8-deep
// software pipeline, masked epilogue.
__global__ void __launch_bounds__(256) pull_split_kernel(
        const float* __restrict__ y,        // split layout [2][N][8]
        const uint2* __restrict__ entries,
        const int* __restrict__ row_ptr,
        float* __restrict__ outp,
        int final_std) {                     // 0: split out, 1: standard [node][16]
    int bx = blockIdx.x;
    int grp = (bx & 7) >> 2;
    int nodeblk = (bx >> 3) * 4 + (bx & 3);
    if (nodeblk >= NODEBLKS) return;
    int t = threadIdx.x;
    int node = nodeblk * 32 + (t >> 3);
    int lane = t & 7;
    const float* yg = y + grp * GSLICE;
    int beg = row_ptr[node];
    int end = row_ptr[node + 1];
    float acc = 0.f;
    if (beg < end) {
        int lim = end - 1;
        uint2 r[8];
        #pragma unroll
        for (int j = 0; j < 8; j++) r[j] = nt_load_u2(&entries[min(beg + j, lim)]);
        int i = beg;
        while (i + 8 <= end) {
            float yv[8];
            #pragma unroll
            for (int j = 0; j < 8; j++)
                yv[j] = yg[(r[j].x & 0x1FFFFu) * 8 + lane];
            uint2 nx[8];
            #pragma unroll
            for (int j = 0; j < 8; j++)
                nx[j] = nt_load_u2(&entries[min(i + 8 + j, lim)]);
            #pragma unroll
            for (int j = 0; j < 8; j++)
                acc += __uint_as_float(r[j].y) * yv[j];
            #pragma unroll
            for (int j = 0; j < 8; j++) r[j] = nx[j];
            i += 8;
        }
        if (i < end) {                       // masked epilogue, still batched
            float yv[8];
            #pragma unroll
            for (int j = 0; j < 8; j++)
                yv[j] = yg[(r[j].x & 0x1FFFFu) * 8 + lane];
            #pragma unroll
            for (int j = 0; j < 8; j++)
                if (i + j < end)
                    acc += __uint_as_float(r[j].y) * yv[j];
        }
    }
    if (final_std) {
        outp[node * BATCH + grp * 8 + lane] = acc;
    } else {
        __builtin_nontemporal_store(acc, &outp[grp * GSLICE + node * 8 + lane]);
    }
}

extern "C" void kernel_launch(void* const* d_in, const int* in_sizes, int n_in,
                              void* d_out, int out_size, void* d_ws, size_t ws_size,
                              hipStream_t stream) {
    const float* x   = (const float*)d_in[0];
    const float* w   = (const float*)d_in[1];
    const int*   row = (const int*)d_in[2];
    const int*   col = (const int*)d_in[3];
    float*       out = (float*)d_out;

    // ---- workspace carve-up (~32.4 MB; proven ws >= 33.2 MB) ----
    char* p = (char*)d_ws;
    uint2* entries = (uint2*)p;  p += (size_t)N_EDGES * sizeof(uint2);           // 25.6 MB
    float* buf     = (float*)p;                                                   // 6.4 MB
    int*   blk_cnt = (int*)buf;  // 1.6 MB alias: dead before L1 writes buf
    p += (size_t)N_NODES * BATCH * sizeof(float);
    int* totals  = (int*)p;      p += 8192;
    int* bptr    = (int*)p;      p += 8192;
    int* row_ptr = (int*)p;      // 400 KB

    // ---- build exact per-node CSR (once; reused by all 4 layers) ----
    hist_kernel<<<NB, 256, 0, stream>>>(row, blk_cnt);
    colscan_kernel<<<(K_BUCKETS + 255) / 256, 256, 0, stream>>>(blk_cnt, totals);
    scan_kernel<<<1, SCAN_T, 0, stream>>>(totals, bptr, row_ptr);
    fill_kernel<<<NB, FT, 0, stream>>>(row, col, w, bptr, blk_cnt, entries);
    nodesort_kernel<<<K_BUCKETS, 256, 0, stream>>>(bptr, entries, row_ptr);

    // ---- transpose x into split layout, staged in d_out (overwritten later)
    split_kernel<<<(N_NODES * BATCH + 255) / 256, 256, 0, stream>>>(x, out);

    // ---- 4 column-sliced pull layers ----
    // split buffers: S0 = d_out region, S1 = buf. No read/write aliasing:
    // L1 S0->S1, L2 S1->S0, L3 S0->S1, L4 S1->d_out(standard).
    const int pgrid = ((NODEBLKS + 3) / 4) * 8;      // 6256 blocks
    pull_split_kernel<<<pgrid, 256, 0, stream>>>(out, entries, row_ptr, buf, 0);
    pull_split_kernel<<<pgrid, 256, 0, stream>>>(buf, entries, row_ptr, out, 0);
    pull_split_kernel<<<pgrid, 256, 0, stream>>>(out, entries, row_ptr, buf, 0);
    pull_split_kernel<<<pgrid, 256, 0, stream>>>(buf, entries, row_ptr, out, 1);
}

// Round 13
// 368.415 us; speedup vs baseline: 1.4497x; 1.4497x over previous
//
#include <hip/hip_runtime.h>

#define N_NODES 100000
#define N_EDGES 3200000
#define BATCH 16
#define BKT_SHIFT 6
#define BKT_NODES 64
#define K_BUCKETS 1563                 // ceil(100000/64)
#define NB 256                         // subchunks (E/NB = 12500 exact)
#define SUB (N_EDGES / NB)             // 12500
#define FT 512                         // fill threads per block (round-9 proven; 1024 FAILED replay validation)
#define SCAN_T 256
#define SCAN_C 7                       // 256*7 = 1792 >= 1563
#define CAP 4096                       // nodesort LDS capacity (bucket avg 2047, sigma 45)
#define PD 12                          // pull pipeline depth (was 8)

// ---- phase 1: per-subchunk LDS histogram of row-buckets ----
__global__ void hist_kernel(const int* __restrict__ row, int* __restrict__ blk_cnt) {
    __shared__ int lh[K_BUCKETS];
    int t = threadIdx.x, blk = blockIdx.x;
    for (int k = t; k < K_BUCKETS; k += 256) lh[k] = 0;
    __syncthreads();
    int base = blk * SUB;
    for (int e = base + t; e < base + SUB; e += 256)
        atomicAdd(&lh[row[e] >> BKT_SHIFT], 1);
    __syncthreads();
    for (int k = t; k < K_BUCKETS; k += 256)
        blk_cnt[k * NB + blk] = lh[k];
}

// ---- phase 2: per-bucket exclusive prefix over the NB subchunks; totals ----
__global__ void colscan_kernel(int* __restrict__ blk_cnt, int* __restrict__ totals) {
    int bkt = blockIdx.x * blockDim.x + threadIdx.x;
    if (bkt >= K_BUCKETS) return;
    int4* p = (int4*)&blk_cnt[bkt * NB];
    int acc = 0;
    for (int q = 0; q < NB / 4; q++) {
        int4 v = p[q];
        int4 o;
        o.x = acc; acc += v.x;
        o.y = acc; acc += v.y;
        o.z = acc; acc += v.z;
        o.w = acc; acc += v.w;
        p[q] = o;
    }
    totals[bkt] = acc;
}

// ---- phase 3: exclusive scan of 1563 bucket totals -> bptr ----
__global__ void scan_kernel(const int* __restrict__ totals, int* __restrict__ bptr,
                            int* __restrict__ row_ptr) {
    __shared__ int s[SCAN_T];
    int t = threadIdx.x;
    int loc[SCAN_C];
    int sum = 0;
    for (int i = 0; i < SCAN_C; i++) {
        int idx = t * SCAN_C + i;
        int v = (idx < K_BUCKETS) ? totals[idx] : 0;
        loc[i] = v;
        sum += v;
    }
    s[t] = sum;
    __syncthreads();
    for (int off = 1; off < SCAN_T; off <<= 1) {   // Hillis-Steele inclusive
        int x = (t >= off) ? s[t - off] : 0;
        __syncthreads();
        s[t] += x;
        __syncthreads();
    }
    int excl = s[t] - sum;
    for (int i = 0; i < SCAN_C; i++) {
        int idx = t * SCAN_C + i;
        if (idx < K_BUCKETS) bptr[idx] = excl;
        excl += loc[i];
    }
    if (t == 0) { bptr[K_BUCKETS] = N_EDGES; row_ptr[N_NODES] = N_EDGES; }
}

// ---- phase 4: LDS counting sort per 12500-edge subchunk, then run copy-out.
// record: x = (r_local<<17)|col (col<2^17), y = w bits.
// FT=512 EXACTLY as round 9 (proven over graph replays). FT=1024 failed
// post-timing validation in round 12 — do not re-raise without a proof.
__global__ void __launch_bounds__(FT) fill_kernel(
        const int* __restrict__ row, const int* __restrict__ col,
        const float* __restrict__ w,
        const int* __restrict__ bptr, const int* __restrict__ blk_cnt,
        uint2* __restrict__ entries) {
    __shared__ uint2 sbuf[SUB];          // 100000 B
    __shared__ int lbeg[K_BUCKETS];      // 6252 B
    __shared__ int lcur[K_BUCKETS];      // 6252 B
    __shared__ int sscan[FT];            // 2048 B   (total 114.5 KB)
    int t = threadIdx.x, blk = blockIdx.x;
    for (int k = t; k < K_BUCKETS; k += FT) lcur[k] = 0;
    __syncthreads();
    int base = blk * SUB;
    // pass 1: histogram into lcur
    for (int e = base + t; e < base + SUB; e += FT)
        atomicAdd(&lcur[row[e] >> BKT_SHIFT], 1);
    __syncthreads();
    // block-wide exclusive scan (each thread owns 4 buckets)
    int loc[4];
    int sum = 0;
    #pragma unroll
    for (int j = 0; j < 4; j++) {
        int k = t * 4 + j;
        int v = (k < K_BUCKETS) ? lcur[k] : 0;
        loc[j] = v;
        sum += v;
    }
    sscan[t] = sum;
    __syncthreads();
    for (int off = 1; off < FT; off <<= 1) {
        int x = (t >= off) ? sscan[t - off] : 0;
        __syncthreads();
        sscan[t] += x;
        __syncthreads();
    }
    int excl = sscan[t] - sum;
    #pragma unroll
    for (int j = 0; j < 4; j++) {
        int k = t * 4 + j;
        if (k < K_BUCKETS) { lbeg[k] = excl; lcur[k] = excl; }
        excl += loc[j];
    }
    __syncthreads();
    // pass 2: place records into LDS (bucket-sorted)
    for (int e = base + t; e < base + SUB; e += FT) {
        int r = row[e];
        int bkt = r >> BKT_SHIFT;
        int pos = atomicAdd(&lcur[bkt], 1);
        sbuf[pos] = make_uint2(((unsigned)(r & (BKT_NODES - 1)) << 17) | (unsigned)col[e],
                               __float_as_uint(w[e]));
    }
    __syncthreads();
    // pass 3: 8-lane subgroups copy each bucket run out (coalesced per run)
    int lane = t & 7;
    for (int k = (t >> 3); k < K_BUCKETS; k += FT / 8) {
        int lb = lbeg[k];
        int le = lcur[k];
        int dst = bptr[k] + blk_cnt[k * NB + blk];
        for (int i = lb + lane; i < le; i += 8)
            entries[dst + (i - lb)] = sbuf[i];
    }
}

// ---- phase 5: in-place per-bucket sort by node (LDS-staged); emits row_ptr ----
__global__ void nodesort_kernel(const int* __restrict__ bptr, uint2* __restrict__ entries,
                                int* __restrict__ row_ptr) {
    __shared__ uint2 ebuf[CAP];          // 32 KB
    __shared__ int nh[BKT_NODES];
    __shared__ int nc[BKT_NODES];
    int t = threadIdx.x, b = blockIdx.x;
    int beg = bptr[b], end = bptr[b + 1];
    int n = min(end - beg, CAP);
    if (t < BKT_NODES) nh[t] = 0;
    __syncthreads();
    for (int k = t; k < n; k += 256) {
        uint2 r = entries[beg + k];
        ebuf[k] = r;
        atomicAdd(&nh[r.x >> 17], 1);
    }
    __syncthreads();
    if (t == 0) {
        int acc = 0;
        for (int i = 0; i < BKT_NODES; i++) {
            int v = nh[i];
            int node = b * BKT_NODES + i;
            if (node < N_NODES) row_ptr[node] = beg + acc;
            nc[i] = acc;
            acc += v;
        }
    }
    __syncthreads();
    for (int k = t; k < n; k += 256) {
        uint2 r = ebuf[k];
        int pos = atomicAdd(&nc[r.x >> 17], 1);
        entries[beg + pos] = r;
    }
}

// ---- layer: node-parallel CSR pull, 12-deep software pipeline, masked
// epilogue. Depth 8 -> 12: round-10 counters (VALUBusy 25%, 1.9 TB/s on
// latency-class gathers) say the pull is in-flight-capacity bound; +50%
// outstanding gathers per wave at ~flat occupancy (VGPR ~90 -> 5 waves/SIMD
// = 1280 thr/CU ~ the 64% occupancy round 9 already showed).
__global__ void __launch_bounds__(256) pull_kernel(const float* __restrict__ y,
                            const uint2* __restrict__ entries,
                            const int* __restrict__ row_ptr,
                            float* __restrict__ out) {
    int tid = blockIdx.x * blockDim.x + threadIdx.x;
    int node = tid >> 4;
    int b = tid & 15;
    if (node >= N_NODES) return;
    int beg = row_ptr[node];
    int end = row_ptr[node + 1];
    float acc = 0.f;
    if (beg < end) {
        int lim = end - 1;
        uint2 r[PD];
        #pragma unroll
        for (int j = 0; j < PD; j++) r[j] = entries[min(beg + j, lim)];
        int i = beg;
        while (i + PD <= end) {
            float yv[PD];
            #pragma unroll
            for (int j = 0; j < PD; j++)
                yv[j] = y[(r[j].x & 0x1FFFFu) * BATCH + b];
            uint2 nx[PD];
            #pragma unroll
            for (int j = 0; j < PD; j++)
                nx[j] = entries[min(i + PD + j, lim)];
            #pragma unroll
            for (int j = 0; j < PD; j++)
                acc += __uint_as_float(r[j].y) * yv[j];
            #pragma unroll
            for (int j = 0; j < PD; j++) r[j] = nx[j];
            i += PD;
        }
        if (i < end) {                       // masked epilogue, still batched
            float yv[PD];
            #pragma unroll
            for (int j = 0; j < PD; j++)
                yv[j] = y[(r[j].x & 0x1FFFFu) * BATCH + b];
            #pragma unroll
            for (int j = 0; j < PD; j++)
                if (i + j < end)
                    acc += __uint_as_float(r[j].y) * yv[j];
        }
    }
    out[node * BATCH + b] = acc;
}

extern "C" void kernel_launch(void* const* d_in, const int* in_sizes, int n_in,
                              void* d_out, int out_size, void* d_ws, size_t ws_size,
                              hipStream_t stream) {
    const float* x   = (const float*)d_in[0];
    const float* w   = (const float*)d_in[1];
    const int*   row = (const int*)d_in[2];
    const int*   col = (const int*)d_in[3];
    float*       out = (float*)d_out;

    // ---- workspace carve-up (~32.4 MB; proven ws >= 33.2 MB) ----
    char* p = (char*)d_ws;
    uint2* entries = (uint2*)p;  p += (size_t)N_EDGES * sizeof(uint2);           // 25.6 MB
    float* buf     = (float*)p;                                                   // 6.4 MB
    int*   blk_cnt = (int*)buf;  // 1.6 MB alias: dead before first pull writes buf
    p += (size_t)N_NODES * BATCH * sizeof(float);
    int* totals  = (int*)p;      p += 8192;
    int* bptr    = (int*)p;      p += 8192;
    int* row_ptr = (int*)p;      // 400 KB

    // ---- build exact per-node CSR (once; reused by all 4 layers) ----
    hist_kernel<<<NB, 256, 0, stream>>>(row, blk_cnt);
    colscan_kernel<<<(K_BUCKETS + 255) / 256, 256, 0, stream>>>(blk_cnt, totals);
    scan_kernel<<<1, SCAN_T, 0, stream>>>(totals, bptr, row_ptr);
    fill_kernel<<<NB, FT, 0, stream>>>(row, col, w, bptr, blk_cnt, entries);
    nodesort_kernel<<<K_BUCKETS, 256, 0, stream>>>(bptr, entries, row_ptr);

    // ---- 4 pull layers; d_out doubles as ping-pong buffer, no memsets ----
    const int pgrid = (N_NODES * BATCH + 255) / 256;   // 6250 blocks
    pull_kernel<<<pgrid, 256, 0, stream>>>(x,   entries, row_ptr, buf);  // x   -> buf
    pull_kernel<<<pgrid, 256, 0, stream>>>(buf, entries, row_ptr, out);  // buf -> out
    pull_kernel<<<pgrid, 256, 0, stream>>>(out, entries, row_ptr, buf);  // out -> buf
    pull_kernel<<<pgrid, 256, 0, stream>>>(buf, entries, row_ptr, out);  // buf -> out
}